// Round 6
// baseline (88.640 us; speedup 1.0000x reference)
//
#include <hip/hip_runtime.h>

// BEVTrans: out[b, c*5+h, d, w] = bilinear_sample(X[b,c], ix(b,w,h,d), iy(b,w,h,d))
//   ix = 319*(c00*wx + c01*hy + c02*dz)/dz,  iy = 95*(c10*wx + c11*hy + c12*dz)/dz
//   (calib row 2 is exactly [0,0,1] in the reference -> z = dz)
// X: [4,256,96,320] f32, calib: [4,3,3] f32, out: [4,1280,100,100] f32
//
// R5: two-kernel split. Kernel 1 (200K threads) computes per-position
// {X offset, out offset, 4 bilinear weights} once into d_ws (4.8 MB).
// Kernel 2 (CG=4 channels/thread, 64 channel-groups) is a pure gather+store
// machine: 2 coalesced coord loads + 16 gathers + 4 nontemporal stores per
// thread, no divides. 4x more waves than R4 for latency hiding; small VGPR
// window so the full 16-load flight stays outstanding.

#define W_IN  320
#define H_IN  96
#define SLICE (H_IN * W_IN)     // 30720 floats per (b,c)
#define NPOS  50000
#define CG    4

typedef float f32x4 __attribute__((ext_vector_type(4)));

__global__ __launch_bounds__(256) void coord_kernel(const float* __restrict__ calib,
                                                    int2* __restrict__ offs,
                                                    f32x4* __restrict__ wts) {
    const int b = blockIdx.z;
    const int t = blockIdx.x * 256 + threadIdx.x;
    if (t >= NPOS) return;

    const int d = t / 500;
    const int r = t - d * 500;
    const int h = r / 100;
    const int w = r - h * 100;

    const float* cb = calib + b * 9;
    const float c00 = cb[0], c01 = cb[1], c02 = cb[2];
    const float c10 = cb[3], c11 = cb[4], c12 = cb[5];

    const float wxv = -9.9f + 0.2f * (float)w;
    const float hyv = -3.0f + (float)h;
    const float dzv = 0.1f + 0.2f * (float)d;
    const float inv = 1.0f / dzv;

    const float ix = 319.0f * inv * (c00 * wxv + c01 * hyv + c02 * dzv);
    const float iy =  95.0f * inv * (c10 * wxv + c11 * hyv + c12 * dzv);
    const float fx0 = floorf(ix), fy0 = floorf(iy);
    const int ix0 = (int)fx0, iy0 = (int)fy0;
    const float ax = ix - fx0, ay = iy - fy0;

    // shifted-weight border handling: weights apply to (xc, xc+1), (yc, yc+1)
    float a0, a1, b0, b1;
    if (ix0 >= 0 && ix0 <= 318)      { a0 = 1.0f - ax; a1 = ax; }
    else if (ix0 == -1)              { a0 = ax;        a1 = 0.0f; }
    else if (ix0 == 319)             { a0 = 0.0f;      a1 = 1.0f - ax; }
    else                             { a0 = 0.0f;      a1 = 0.0f; }
    if (iy0 >= 0 && iy0 <= 94)       { b0 = 1.0f - ay; b1 = ay; }
    else if (iy0 == -1)              { b0 = ay;        b1 = 0.0f; }
    else if (iy0 == 95)              { b0 = 0.0f;      b1 = 1.0f - ay; }
    else                             { b0 = 0.0f;      b1 = 0.0f; }

    const int xc = min(max(ix0, 0), 318);
    const int yc = min(max(iy0, 0), 94);

    offs[b * NPOS + t] = make_int2(yc * W_IN + xc, h * 10000 + d * 100 + w);
    f32x4 wv = { a0 * b0, a1 * b0, a0 * b1, a1 * b1 };
    wts[b * NPOS + t] = wv;
}

__global__ __launch_bounds__(256) void gather_kernel(const float* __restrict__ X,
                                                     const int2* __restrict__ offs,
                                                     const f32x4* __restrict__ wts,
                                                     float* __restrict__ out) {
    const int b  = blockIdx.z;
    const int c0 = blockIdx.y * CG;
    const int t  = blockIdx.x * 256 + threadIdx.x;
    if (t >= NPOS) return;

    const int2  io = offs[b * NPOS + t];
    const f32x4 wt = wts[b * NPOS + t];

    const float* Xc = X + ((size_t)b * 256 + (size_t)c0) * SLICE + io.x;
    float* oc = out + (size_t)b * 12800000 + (size_t)c0 * 50000 + io.y;

    if (wt.x + wt.y + wt.z + wt.w > 0.0f) {
        float v00[CG], v01[CG], v10[CG], v11[CG];
        #pragma unroll
        for (int cc = 0; cc < CG; ++cc) {
            const float* p = Xc + (size_t)cc * SLICE;
            v00[cc] = p[0];
            v01[cc] = p[1];
            v10[cc] = p[320];
            v11[cc] = p[321];
        }
        #pragma unroll
        for (int cc = 0; cc < CG; ++cc) {
            float v = wt.x * v00[cc];
            v = fmaf(wt.y, v01[cc], v);
            v = fmaf(wt.z, v10[cc], v);
            v = fmaf(wt.w, v11[cc], v);
            __builtin_nontemporal_store(v, oc + (size_t)cc * 50000);
        }
    } else {
        #pragma unroll
        for (int cc = 0; cc < CG; ++cc) {
            __builtin_nontemporal_store(0.0f, oc + (size_t)cc * 50000);
        }
    }
}

extern "C" void kernel_launch(void* const* d_in, const int* in_sizes, int n_in,
                              void* d_out, int out_size, void* d_ws, size_t ws_size,
                              hipStream_t stream) {
    const float* X     = (const float*)d_in[0];   // [4,256,96,320]
    const float* calib = (const float*)d_in[1];   // [4,3,3]
    float* out = (float*)d_out;                   // [4,1280,100,100]

    int2*  offs = (int2*)d_ws;                                  // 4*50000*8  = 1.6 MB
    f32x4* wts  = (f32x4*)((char*)d_ws + 4 * NPOS * sizeof(int2)); // +3.2 MB (16B-aligned)

    dim3 g1((NPOS + 255) / 256, 1, 4);
    coord_kernel<<<g1, dim3(256), 0, stream>>>(calib, offs, wts);

    dim3 g2((NPOS + 255) / 256, 256 / CG, 4);    // 196 x 64 x 4 = 50176 blocks
    gather_kernel<<<g2, dim3(256), 0, stream>>>(X, offs, wts, out);
}